// Round 20
// baseline (107.810 us; speedup 1.0000x reference)
//
#include <hip/hip_runtime.h>

typedef __bf16 bf16;
typedef bf16 bf16x8 __attribute__((ext_vector_type(8)));
typedef float f32x4 __attribute__((ext_vector_type(4)));

#define TPM 256    // block size (4 waves)
#define UPAD 136   // u-scratch row stride in ushorts

#define NPB   1024 // pool blocks: 32 batches x 32 groups of 16 clusters (short blocks)
#define NGB   512  // gmean blocks: 32 batches x 16 chunks of 256 rows
#define NAUX  (NPB + NGB)
#define NM0   2048 // fine-path mega blocks: (32*4096)/64
#define NM1   256  // coarse-path mega blocks: (32*512)/64

__device__ inline unsigned short f2bf(float f){
  union{ bf16 h; unsigned short u; } v; v.h = (bf16)f; return v.u;
}
__device__ inline float bf2f(unsigned short u){
  union{ unsigned short u; bf16 h; } v; v.u = u; return (float)v.h;
}
__device__ inline unsigned int pk2(float a, float b){
  return (unsigned int)f2bf(a) | ((unsigned int)f2bf(b) << 16);
}
union BF8 { bf16x8 v; unsigned int u[4]; };
__device__ inline bf16x8 pack8(float4 a, float4 b){
  BF8 r; r.u[0] = pk2(a.x, a.y); r.u[1] = pk2(a.z, a.w);
  r.u[2] = pk2(b.x, b.y); r.u[3] = pk2(b.z, b.w); return r.v;
}

// ---- async global->LDS staging (no VGPR round-trip; drained by __syncthreads) ----
__device__ inline void gll16(const unsigned short* g, unsigned short* l){
  __builtin_amdgcn_global_load_lds(
      (const __attribute__((address_space(1))) unsigned int*)g,
      (__attribute__((address_space(3))) unsigned int*)l, 16, 0, 0);
}
// stage one 16KB half-window (16 frags of 512 ushorts): 4 gll16 per thread at 256 thr
__device__ inline void stage_win(const unsigned short* __restrict__ src,
                                 unsigned short* half, int tid){
#pragma unroll
  for (int i = 0; i < 4; ++i){
    int p = (tid + i*TPM)*8;
    gll16(src + p, half + p);
  }
}

// one 64-K chunk (16 MFMA) for a 16x128 wave tile; B from a 16KB half-window
__device__ inline void gemm_win(const bf16x8 a[2], const unsigned short* half,
                                f32x4 acc[8], int lane){
#pragma unroll
  for (int kk = 0; kk < 2; ++kk){
    bf16x8 av = a[kk];
#pragma unroll
    for (int n = 0; n < 8; ++n){
      bf16x8 bv = *(const bf16x8*)(half + (size_t)((n*2 + kk)*512) + lane*8);
      acc[n] = __builtin_amdgcn_mfma_f32_16x16x32_bf16(av, bv, acc[n], 0, 0, 0);
    }
  }
}

// per-row LN stats, in-wave (rows = lg*4+ri, cols = n*16+il)
__device__ inline void rowstats(const f32x4 acc[8], const float bia[8],
                                float mean[4], float rstd[4]){
#pragma unroll
  for (int ri = 0; ri < 4; ++ri){
    float s = 0.f, q = 0.f;
#pragma unroll
    for (int n = 0; n < 8; ++n){
      float z = acc[n][ri] + bia[n];
      s += z; q += z*z;
    }
#pragma unroll
    for (int m = 1; m < 16; m <<= 1){ s += __shfl_xor(s, m); q += __shfl_xor(q, m); }
    mean[ri] = s * (1.f/128.f);
    float var = q * (1.f/128.f) - mean[ri]*mean[ri];
    rstd[ri] = rsqrtf(var + 1e-5f);
  }
}

// =======================  aux bodies  =======================
struct PoolSh {
  int sidx[4096];
  int rows[4096];
  int cnt[16], off[17], woff[16];
};
struct GmeanSh { float4 part4[8][32]; };

// CSR segment-mean, 256 thr, 16 clusters/block (8 half-waves x 2 serial clusters)
__device__ void pool_body(PoolSh& sh, int pid,
                          const float* __restrict__ fine,
                          const int* __restrict__ idx,
                          unsigned short* __restrict__ pooled){
  int b = pid >> 5, g = pid & 31;
  int c0 = g * 16;
  int tid = threadIdx.x;
  const int* idx_b = idx + b*4096;
#pragma unroll
  for (int i = 0; i < 4; ++i)
    ((int4*)sh.sidx)[tid + i*TPM] = ((const int4*)idx_b)[tid + i*TPM];
  if (tid < 16) sh.cnt[tid] = 0;
  __syncthreads();
  for (int i = tid; i < 4096; i += TPM){
    unsigned d = (unsigned)(sh.sidx[i] - c0);
    if (d < 16u) atomicAdd(&sh.cnt[d], 1);
  }
  __syncthreads();
  if (tid == 0){
    int s = 0;
#pragma unroll
    for (int j = 0; j < 16; ++j){ sh.off[j] = s; s += sh.cnt[j]; }
    sh.off[16] = s;
  }
  __syncthreads();
  if (tid < 16) sh.woff[tid] = sh.off[tid];
  __syncthreads();
  for (int i = tid; i < 4096; i += TPM){
    unsigned d = (unsigned)(sh.sidx[i] - c0);
    if (d < 16u){ int p = atomicAdd(&sh.woff[d], 1); sh.rows[p] = i; }
  }
  __syncthreads();
  int hw = tid >> 5, l32 = tid & 31;
  const float* fb = fine + (size_t)b*4096*128;
#pragma unroll
  for (int s2 = 0; s2 < 2; ++s2){
    int cl = hw + s2*8;
    int o0 = sh.off[cl], o1 = sh.off[cl+1];
    float4 s = {0.f, 0.f, 0.f, 0.f};
    int m = o0;
    for (; m + 3 < o1; m += 4){               // 4 independent row-loads in flight
      float4 v0 = *((const float4*)(fb + (size_t)sh.rows[m+0]*128) + l32);
      float4 v1 = *((const float4*)(fb + (size_t)sh.rows[m+1]*128) + l32);
      float4 v2 = *((const float4*)(fb + (size_t)sh.rows[m+2]*128) + l32);
      float4 v3 = *((const float4*)(fb + (size_t)sh.rows[m+3]*128) + l32);
      s.x += (v0.x + v1.x) + (v2.x + v3.x);
      s.y += (v0.y + v1.y) + (v2.y + v3.y);
      s.z += (v0.z + v1.z) + (v2.z + v3.z);
      s.w += (v0.w + v1.w) + (v2.w + v3.w);
    }
    for (; m < o1; ++m){
      float4 v = *((const float4*)(fb + (size_t)sh.rows[m]*128) + l32);
      s.x += v.x; s.y += v.y; s.z += v.z; s.w += v.w;
    }
    float inv = 1.f / fmaxf((float)(o1 - o0), 1.f);
    unsigned short* po = pooled + ((size_t)(b*512 + c0 + cl))*128 + l32*4;
    uint2 w2; w2.x = pk2(s.x*inv, s.y*inv); w2.y = pk2(s.z*inv, s.w*inv);
    *(uint2*)po = w2;
  }
}

// per-batch glob sum, 256 thr, 256 rows/block
__device__ void gmean_body(GmeanSh& sh, int gid,
                           const float* __restrict__ glob,
                           float* __restrict__ gmean){
  int b = gid >> 4, ch = gid & 15;
  int tid = threadIdx.x;
  int c4 = tid & 31, rg = tid >> 5;
  const float* gb = glob + ((size_t)b*4096 + ch*256)*128;
  float4 a = {0.f, 0.f, 0.f, 0.f};
#pragma unroll
  for (int i = 0; i < 32; ++i){
    int r = rg + i*8;
    float4 v = *(const float4*)(gb + (size_t)r*128 + c4*4);
    a.x += v.x; a.y += v.y; a.z += v.z; a.w += v.w;
  }
  sh.part4[rg][c4] = a;
  __syncthreads();
  if (tid < 32){
    float4 s = sh.part4[0][tid];
#pragma unroll
    for (int g = 1; g < 8; ++g){
      float4 v = sh.part4[g][tid];
      s.x += v.x; s.y += v.y; s.z += v.z; s.w += v.w;
    }
    float* gm = gmean + b*128 + tid*4;
    atomicAdd(&gm[0], s.x); atomicAdd(&gm[1], s.y);
    atomicAdd(&gm[2], s.z); atomicAdd(&gm[3], s.w);
  }
}

// W [K][128] fp32 -> 16KB-window-ordered bf16 (frag = c*16 + nblk*2 + kk; 512 ushorts/frag)
__global__ __launch_bounds__(TPM) void k_prep(
    const float* __restrict__ Wp, const float* __restrict__ Wu,
    const float* __restrict__ Wg, const float* __restrict__ Wgl,
    unsigned short* __restrict__ WfP, unsigned short* __restrict__ WfU,
    unsigned short* __restrict__ WfG, unsigned short* __restrict__ WfGl){
  int e = blockIdx.x * TPM + threadIdx.x;      // 0..32767
  int j = e & 7, lane = (e >> 3) & 63, frag = e >> 9;
  int kk = frag & 1, nblk = (frag >> 1) & 7, c = frag >> 4;
  int il = lane & 15, lg = lane >> 4;
  int col = nblk*16 + il;
  int k = c*64 + kk*32 + lg*8 + j;
  if (e < 16384){
    WfP[e] = f2bf(Wp[k*128 + col]);
    WfU[e] = f2bf(Wu[k*128 + col]);
  }
  WfG[e]  = f2bf(Wg[k*128 + col]);
  WfGl[e] = f2bf(Wgl[k*128 + col]);
}

// ==========  mega body: R18's 10-phase, 4 waves / 64 rows (verified)  ==========
struct MegaSh {
  unsigned short wb[2][8192];      // 2 x 16 KB weight windows
  unsigned short ubuf[4][16*UPAD]; // per-wave u scratch (17.4 KB)
};                                 // 49.4 KB -> 3 blocks/CU
template<int PATH>   // 0 = fine path, 1 = coarse path
__device__ void mega_body(MegaSh& sh, int bid,
    const float* __restrict__ a_src,
    const float* __restrict__ gath_src,
    const unsigned short* __restrict__ x1b,
    const int* __restrict__ idx,
    const float* __restrict__ gsrc,
    float gscale,
    const unsigned short* __restrict__ Wf1, const float* __restrict__ b1,
    const float* __restrict__ g1, const float* __restrict__ be1,
    const unsigned short* __restrict__ WfG, const float* __restrict__ bG,
    const unsigned short* __restrict__ WfGl, const float* __restrict__ bGl,
    const float* __restrict__ gGl, const float* __restrict__ beGl,
    float* __restrict__ out)
{
  int tid = threadIdx.x;
  int wave = tid >> 6, lane = tid & 63;
  int il = lane & 15, lg = lane >> 4;
  int row0 = bid * 64 + wave * 16;
  int b = (PATH == 0) ? (row0 >> 12) : (row0 >> 9);
  unsigned short* u = sh.ubuf[wave];

  // ===== prologue: stage w0 (W1 lo) + A1 loads =====
  stage_win(Wf1, sh.wb[0], tid);
  bf16x8 a1[4];
  if (PATH == 0){
    int n0 = row0 & 4095;
    int ci = idx[b*4096 + n0 + il];
    bool valid = (unsigned)ci < 512u;
    const float* cr = gath_src + ((size_t)b*512 + (valid ? ci : 0))*128;
#pragma unroll
    for (int c = 0; c < 2; ++c)
#pragma unroll
      for (int kk = 0; kk < 2; ++kk){
        float4 f0 = {0.f,0.f,0.f,0.f}, f1 = {0.f,0.f,0.f,0.f};
        if (valid){
          f0 = *(const float4*)(cr + c*64 + kk*32 + lg*8);
          f1 = *(const float4*)(cr + c*64 + kk*32 + lg*8 + 4);
        }
        a1[c*2 + kk] = pack8(f0, f1);
      }
  } else {
    const unsigned short* pr = x1b + (size_t)(row0 + il)*128;
#pragma unroll
    for (int c = 0; c < 2; ++c)
#pragma unroll
      for (int kk = 0; kk < 2; ++kk)
        a1[c*2 + kk] = *(const bf16x8*)(pr + c*64 + kk*32 + lg*8);
  }
  __syncthreads();                              // w0 ready

  f32x4 acc[8] = {};
  bf16x8 af[2];
  float4 raw[8];
  const float* ar = a_src + (size_t)(row0 + il)*128;

  // ph0: stage w1 (W1 hi) | compute w0 (GEMM1 c0)
  stage_win(Wf1 + 8192, sh.wb[1], tid);
  af[0] = a1[0]; af[1] = a1[1];
  gemm_win(af, sh.wb[0], acc, lane);
  __syncthreads();

  // ph1: stage w2 (WG c0) | compute w1 (GEMM1 c1) + raw prefetch + LN1
  stage_win(WfG, sh.wb[0], tid);
  af[0] = a1[2]; af[1] = a1[3];
  gemm_win(af, sh.wb[1], acc, lane);
#pragma unroll
  for (int c = 0; c < 2; ++c)
#pragma unroll
    for (int kk = 0; kk < 2; ++kk){
      raw[(c*2+kk)*2+0] = *(const float4*)(ar + c*64 + kk*32 + lg*8);
      raw[(c*2+kk)*2+1] = *(const float4*)(ar + c*64 + kk*32 + lg*8 + 4);
    }
  {
    float bia[8], gmv[8], btv[8];
#pragma unroll
    for (int n = 0; n < 8; ++n){
      int col = n*16 + il;
      bia[n] = b1[col]; gmv[n] = g1[col]; btv[n] = be1[col];
    }
    float mean[4], rstd[4];
    rowstats(acc, bia, mean, rstd);
#pragma unroll
    for (int ri = 0; ri < 4; ++ri)
#pragma unroll
      for (int n = 0; n < 8; ++n){
        float z = acc[n][ri] + bia[n];
        float y = fmaxf((z - mean[ri])*rstd[ri]*gmv[n] + btv[n], 0.f);
        u[(lg*4 + ri)*UPAD + n*16 + il] = f2bf(y);
      }
  }
  __syncthreads();

  // ph2: stage w3 (WG c1) | compute w2 (GEMM2 c0 from a)
  stage_win(WfG + 8192, sh.wb[1], tid);
#pragma unroll
  for (int n = 0; n < 8; ++n) acc[n] = (f32x4){0.f,0.f,0.f,0.f};
  af[0] = pack8(raw[0], raw[1]); af[1] = pack8(raw[2], raw[3]);
  gemm_win(af, sh.wb[0], acc, lane);
  __syncthreads();

  // ph3: stage w4 (WG c2) | compute w3 (GEMM2 c1 from a)
  stage_win(WfG + 16384, sh.wb[0], tid);
  af[0] = pack8(raw[4], raw[5]); af[1] = pack8(raw[6], raw[7]);
  gemm_win(af, sh.wb[1], acc, lane);
  __syncthreads();

  // ph4: stage w5 (WG c3) | compute w4 (GEMM2 c2 from u1) + GEMM3-A prefetch
  stage_win(WfG + 24576, sh.wb[1], tid);
  if (PATH == 0){
    const float* gr = gsrc + (size_t)(row0 + il)*128;
#pragma unroll
    for (int c = 0; c < 2; ++c)
#pragma unroll
      for (int kk = 0; kk < 2; ++kk){
        raw[(c*2+kk)*2+0] = *(const float4*)(gr + c*64 + kk*32 + lg*8);
        raw[(c*2+kk)*2+1] = *(const float4*)(gr + c*64 + kk*32 + lg*8 + 4);
      }
  } else {
    const float* gm = gsrc + b*128;
#pragma unroll
    for (int c = 0; c < 2; ++c)
#pragma unroll
      for (int kk = 0; kk < 2; ++kk){
        float4 f0 = *(const float4*)(gm + c*64 + kk*32 + lg*8);
        float4 f1 = *(const float4*)(gm + c*64 + kk*32 + lg*8 + 4);
        raw[(c*2+kk)*2+0] = (float4){f0.x*gscale, f0.y*gscale, f0.z*gscale, f0.w*gscale};
        raw[(c*2+kk)*2+1] = (float4){f1.x*gscale, f1.y*gscale, f1.z*gscale, f1.w*gscale};
      }
  }
  af[0] = *(const bf16x8*)(u + il*UPAD + 0*64 + 0*32 + lg*8);
  af[1] = *(const bf16x8*)(u + il*UPAD + 0*64 + 1*32 + lg*8);
  gemm_win(af, sh.wb[0], acc, lane);
  __syncthreads();

  // ph5: stage w6 (WGl c0) | compute w5 (GEMM2 c3 from u1) + gate epilogue
  stage_win(WfGl, sh.wb[0], tid);
  af[0] = *(const bf16x8*)(u + il*UPAD + 1*64 + 0*32 + lg*8);
  af[1] = *(const bf16x8*)(u + il*UPAD + 1*64 + 1*32 + lg*8);
  gemm_win(af, sh.wb[1], acc, lane);
#pragma unroll
  for (int ri = 0; ri < 4; ++ri){
    int grow = (row0 + lg*4 + ri)*128;
#pragma unroll
    for (int n = 0; n < 8; ++n){
      int col = n*16 + il;
      float z = acc[n][ri] + bG[col];
      float gt = 1.f / (1.f + __expf(-z));
      float f  = a_src[(size_t)grow + col];
      int ua = (lg*4 + ri)*UPAD + col;
      float u1 = bf2f(u[ua]);
      u[ua] = f2bf(gt*f + (1.f - gt)*u1);       // own addr: per-lane RMW
    }
  }
  __syncthreads();

  // ph6: stage w7 (WGl c1) | compute w6 (GEMM3 c0 from u2)
  stage_win(WfGl + 8192, sh.wb[1], tid);
#pragma unroll
  for (int n = 0; n < 8; ++n) acc[n] = (f32x4){0.f,0.f,0.f,0.f};
  af[0] = *(const bf16x8*)(u + il*UPAD + 0*64 + 0*32 + lg*8);
  af[1] = *(const bf16x8*)(u + il*UPAD + 0*64 + 1*32 + lg*8);
  gemm_win(af, sh.wb[0], acc, lane);
  __syncthreads();

  // ph7: stage w8 (WGl c2) | compute w7 (GEMM3 c1 from u2)
  stage_win(WfGl + 16384, sh.wb[0], tid);
  af[0] = *(const bf16x8*)(u + il*UPAD + 1*64 + 0*32 + lg*8);
  af[1] = *(const bf16x8*)(u + il*UPAD + 1*64 + 1*32 + lg*8);
  gemm_win(af, sh.wb[1], acc, lane);
  __syncthreads();

  // ph8: stage w9 (WGl c3) | compute w8 (GEMM3 c2 from glob)
  stage_win(WfGl + 24576, sh.wb[1], tid);
  af[0] = pack8(raw[0], raw[1]); af[1] = pack8(raw[2], raw[3]);
  gemm_win(af, sh.wb[0], acc, lane);
  __syncthreads();

  // ph9: compute w9 (GEMM3 c3 from glob) + final epilogue
  af[0] = pack8(raw[4], raw[5]); af[1] = pack8(raw[6], raw[7]);
  gemm_win(af, sh.wb[1], acc, lane);
  {
    float bia[8], gmv[8], btv[8];
#pragma unroll
    for (int n = 0; n < 8; ++n){
      int col = n*16 + il;
      bia[n] = bGl[col]; gmv[n] = gGl[col]; btv[n] = beGl[col];
    }
    float mean[4], rstd[4];
    rowstats(acc, bia, mean, rstd);
#pragma unroll
    for (int ri = 0; ri < 4; ++ri){
      int grow = (row0 + lg*4 + ri)*128;
#pragma unroll
      for (int n = 0; n < 8; ++n){
        int col = n*16 + il;
        float z = acc[n][ri] + bia[n];
        float y = fmaxf((z - mean[ri])*rstd[ri]*gmv[n] + btv[n], 0.f);
        float u2 = bf2f(u[(lg*4 + ri)*UPAD + col]);
        out[(size_t)grow + col] = u2 + 0.1f*y;
      }
    }
  }
}

union MainSh { MegaSh m; PoolSh p; GmeanSh g; };

// Main dispatch: [0,NPB) pool; [NPB,NAUX) gmean; [NAUX, NAUX+NM0) fine mega.
// Aux blocks FIRST: short, memory-heavy, overlap into mega's latency slack; no tail.
// pool/gmean outputs are consumed only by k_coarse (next dispatch) -> no ordering race.
__global__ __launch_bounds__(TPM, 3) void k_main(
    const float* __restrict__ fine,
    const float* __restrict__ coarse,
    const int* __restrict__ idx,
    const float* __restrict__ glob,
    const unsigned short* __restrict__ WfU, const float* __restrict__ bU,
    const float* __restrict__ gU, const float* __restrict__ beU,
    const unsigned short* __restrict__ WfG, const float* __restrict__ bG,
    const unsigned short* __restrict__ WfGl, const float* __restrict__ bGl,
    const float* __restrict__ gGl, const float* __restrict__ beGl,
    unsigned short* __restrict__ pooled,
    float* __restrict__ gmean,
    float* __restrict__ out_fine)
{
  __shared__ __align__(16) MainSh sh;
  int bid = blockIdx.x;
  if (bid < NPB){
    pool_body(sh.p, bid, fine, idx, pooled);
  } else if (bid < NAUX){
    gmean_body(sh.g, bid - NPB, glob, gmean);
  } else {
    mega_body<0>(sh.m, bid - NAUX, fine, coarse, nullptr, idx, glob, 1.0f,
                 WfU, bU, gU, beU, WfG, bG, WfGl, bGl, gGl, beGl, out_fine);
  }
}

// coarse path dispatch (consumes pooled/gmean from k_main)
__global__ __launch_bounds__(TPM, 3) void k_coarse(
    const float* __restrict__ coarse,
    const unsigned short* __restrict__ pooled,
    const float* __restrict__ gmean,
    const unsigned short* __restrict__ WfP, const float* __restrict__ bP,
    const float* __restrict__ gP, const float* __restrict__ beP,
    const unsigned short* __restrict__ WfG, const float* __restrict__ bG,
    const unsigned short* __restrict__ WfGl, const float* __restrict__ bGl,
    const float* __restrict__ gGl, const float* __restrict__ beGl,
    float* __restrict__ out_coarse)
{
  __shared__ __align__(16) MegaSh sh;
  mega_body<1>(sh, blockIdx.x, coarse, nullptr, pooled, nullptr, gmean, 1.f/4096.f,
               WfP, bP, gP, beP, WfG, bG, WfGl, bGl, gGl, beGl, out_coarse);
}

extern "C" void kernel_launch(void* const* d_in, const int* in_sizes, int n_in,
                              void* d_out, int out_size, void* d_ws, size_t ws_size,
                              hipStream_t stream){
  const float* fine    = (const float*)d_in[0];
  const float* coarse  = (const float*)d_in[1];
  const float* glob    = (const float*)d_in[2];
  const int*   idx     = (const int*)  d_in[3];
  const float* W_pool  = (const float*)d_in[4];
  const float* b_pool  = (const float*)d_in[5];
  const float* g_pool  = (const float*)d_in[6];
  const float* be_pool = (const float*)d_in[7];
  const float* W_unpool  = (const float*)d_in[8];
  const float* b_unpool  = (const float*)d_in[9];
  const float* g_unpool  = (const float*)d_in[10];
  const float* be_unpool = (const float*)d_in[11];
  const float* W_gate = (const float*)d_in[12];
  const float* b_gate = (const float*)d_in[13];
  const float* W_glob = (const float*)d_in[14];
  const float* b_glob = (const float*)d_in[15];
  const float* g_glob = (const float*)d_in[16];
  const float* be_glob= (const float*)d_in[17];

  const int B = 32, N = 4096, C = 512;
  float* out_fine   = (float*)d_out;
  float* out_coarse = out_fine + (size_t)B*N*128;

  char* w = (char*)d_ws;
  unsigned short* WfP  = (unsigned short*)w; w += 16384*2;
  unsigned short* WfU  = (unsigned short*)w; w += 16384*2;
  unsigned short* WfG  = (unsigned short*)w; w += 32768*2;
  unsigned short* WfGl = (unsigned short*)w; w += 32768*2;
  float* gmean = (float*)w;                  w += B*128*4;
  unsigned short* pooled = (unsigned short*)w; w += (size_t)B*C*128*2;

  hipMemsetAsync(gmean, 0, B*128*4, stream);
  // 1) weight prep only (fine path's sole prologue dependency)
  k_prep<<<128, TPM, 0, stream>>>(W_pool, W_unpool, W_gate, W_glob, WfP, WfU, WfG, WfGl);

  // 2) main: pool + gmean first (short blocks, overlap), then fine-path mega
  k_main<<<NAUX + NM0, TPM, 0, stream>>>(
      fine, coarse, idx, glob,
      WfU, b_unpool, g_unpool, be_unpool,
      WfG, b_gate, WfGl, b_glob, g_glob, be_glob,
      pooled, gmean, out_fine);

  // 3) coarse path (needs pooled + gmean)
  k_coarse<<<NM1, TPM, 0, stream>>>(
      coarse, pooled, gmean,
      WfP, b_pool, g_pool, be_pool,
      WfG, b_gate, WfGl, b_glob, g_glob, be_glob,
      out_coarse);
}

// Round 21
// 106.583 us; speedup vs baseline: 1.0115x; 1.0115x over previous
//
#include <hip/hip_runtime.h>

typedef __bf16 bf16;
typedef bf16 bf16x8 __attribute__((ext_vector_type(8)));
typedef float f32x4 __attribute__((ext_vector_type(4)));

#define TPM 256    // block size (4 waves)
#define UPAD 136   // u-scratch row stride in ushorts

#define NPB   1024 // pool blocks: 32 batches x 32 groups of 16 clusters
#define NGB   512  // gmean blocks: 32 batches x 16 chunks of 256 rows
#define NM0   2048 // fine-path mega blocks: (32*4096)/64
#define NM1   256  // coarse-path mega blocks: (32*512)/64
// k_main grid: 3584 = 7*512 groups of {4 mega, 3 aux} interleaved

__device__ inline unsigned short f2bf(float f){
  union{ bf16 h; unsigned short u; } v; v.h = (bf16)f; return v.u;
}
__device__ inline float bf2f(unsigned short u){
  union{ unsigned short u; bf16 h; } v; v.u = u; return (float)v.h;
}
__device__ inline unsigned int pk2(float a, float b){
  return (unsigned int)f2bf(a) | ((unsigned int)f2bf(b) << 16);
}
union BF8 { bf16x8 v; unsigned int u[4]; };
__device__ inline bf16x8 pack8(float4 a, float4 b){
  BF8 r; r.u[0] = pk2(a.x, a.y); r.u[1] = pk2(a.z, a.w);
  r.u[2] = pk2(b.x, b.y); r.u[3] = pk2(b.z, b.w); return r.v;
}

// ---- async global->LDS staging (no VGPR round-trip; drained by __syncthreads) ----
__device__ inline void gll16(const unsigned short* g, unsigned short* l){
  __builtin_amdgcn_global_load_lds(
      (const __attribute__((address_space(1))) unsigned int*)g,
      (__attribute__((address_space(3))) unsigned int*)l, 16, 0, 0);
}
// stage one 16KB half-window (16 frags of 512 ushorts): 4 gll16 per thread at 256 thr
__device__ inline void stage_win(const unsigned short* __restrict__ src,
                                 unsigned short* half, int tid){
#pragma unroll
  for (int i = 0; i < 4; ++i){
    int p = (tid + i*TPM)*8;
    gll16(src + p, half + p);
  }
}

// one 64-K chunk (16 MFMA) for a 16x128 wave tile; B from a 16KB half-window
__device__ inline void gemm_win(const bf16x8 a[2], const unsigned short* half,
                                f32x4 acc[8], int lane){
#pragma unroll
  for (int kk = 0; kk < 2; ++kk){
    bf16x8 av = a[kk];
#pragma unroll
    for (int n = 0; n < 8; ++n){
      bf16x8 bv = *(const bf16x8*)(half + (size_t)((n*2 + kk)*512) + lane*8);
      acc[n] = __builtin_amdgcn_mfma_f32_16x16x32_bf16(av, bv, acc[n], 0, 0, 0);
    }
  }
}

// per-row LN stats, in-wave (rows = lg*4+ri, cols = n*16+il)
__device__ inline void rowstats(const f32x4 acc[8], const float bia[8],
                                float mean[4], float rstd[4]){
#pragma unroll
  for (int ri = 0; ri < 4; ++ri){
    float s = 0.f, q = 0.f;
#pragma unroll
    for (int n = 0; n < 8; ++n){
      float z = acc[n][ri] + bia[n];
      s += z; q += z*z;
    }
#pragma unroll
    for (int m = 1; m < 16; m <<= 1){ s += __shfl_xor(s, m); q += __shfl_xor(q, m); }
    mean[ri] = s * (1.f/128.f);
    float var = q * (1.f/128.f) - mean[ri]*mean[ri];
    rstd[ri] = rsqrtf(var + 1e-5f);
  }
}

// =======================  aux bodies (verified R20)  =======================
struct PoolSh {
  int sidx[4096];
  int rows[4096];
  int cnt[16], off[17], woff[16];
};
struct GmeanSh { float4 part4[8][32]; };

// CSR segment-mean, 256 thr, 16 clusters/block (8 half-waves x 2 serial clusters)
__device__ void pool_body(PoolSh& sh, int pid,
                          const float* __restrict__ fine,
                          const int* __restrict__ idx,
                          unsigned short* __restrict__ pooled){
  int b = pid >> 5, g = pid & 31;
  int c0 = g * 16;
  int tid = threadIdx.x;
  const int* idx_b = idx + b*4096;
#pragma unroll
  for (int i = 0; i < 4; ++i)
    ((int4*)sh.sidx)[tid + i*TPM] = ((const int4*)idx_b)[tid + i*TPM];
  if (tid < 16) sh.cnt[tid] = 0;
  __syncthreads();
  for (int i = tid; i < 4096; i += TPM){
    unsigned d = (unsigned)(sh.sidx[i] - c0);
    if (d < 16u) atomicAdd(&sh.cnt[d], 1);
  }
  __syncthreads();
  if (tid == 0){
    int s = 0;
#pragma unroll
    for (int j = 0; j < 16; ++j){ sh.off[j] = s; s += sh.cnt[j]; }
    sh.off[16] = s;
  }
  __syncthreads();
  if (tid < 16) sh.woff[tid] = sh.off[tid];
  __syncthreads();
  for (int i = tid; i < 4096; i += TPM){
    unsigned d = (unsigned)(sh.sidx[i] - c0);
    if (d < 16u){ int p = atomicAdd(&sh.woff[d], 1); sh.rows[p] = i; }
  }
  __syncthreads();
  int hw = tid >> 5, l32 = tid & 31;
  const float* fb = fine + (size_t)b*4096*128;
#pragma unroll
  for (int s2 = 0; s2 < 2; ++s2){
    int cl = hw + s2*8;
    int o0 = sh.off[cl], o1 = sh.off[cl+1];
    float4 s = {0.f, 0.f, 0.f, 0.f};
    int m = o0;
    for (; m + 3 < o1; m += 4){               // 4 independent row-loads in flight
      float4 v0 = *((const float4*)(fb + (size_t)sh.rows[m+0]*128) + l32);
      float4 v1 = *((const float4*)(fb + (size_t)sh.rows[m+1]*128) + l32);
      float4 v2 = *((const float4*)(fb + (size_t)sh.rows[m+2]*128) + l32);
      float4 v3 = *((const float4*)(fb + (size_t)sh.rows[m+3]*128) + l32);
      s.x += (v0.x + v1.x) + (v2.x + v3.x);
      s.y += (v0.y + v1.y) + (v2.y + v3.y);
      s.z += (v0.z + v1.z) + (v2.z + v3.z);
      s.w += (v0.w + v1.w) + (v2.w + v3.w);
    }
    for (; m < o1; ++m){
      float4 v = *((const float4*)(fb + (size_t)sh.rows[m]*128) + l32);
      s.x += v.x; s.y += v.y; s.z += v.z; s.w += v.w;
    }
    float inv = 1.f / fmaxf((float)(o1 - o0), 1.f);
    unsigned short* po = pooled + ((size_t)(b*512 + c0 + cl))*128 + l32*4;
    uint2 w2; w2.x = pk2(s.x*inv, s.y*inv); w2.y = pk2(s.z*inv, s.w*inv);
    *(uint2*)po = w2;
  }
}

// per-batch glob sum, 256 thr, 256 rows/block
__device__ void gmean_body(GmeanSh& sh, int gid,
                           const float* __restrict__ glob,
                           float* __restrict__ gmean){
  int b = gid >> 4, ch = gid & 15;
  int tid = threadIdx.x;
  int c4 = tid & 31, rg = tid >> 5;
  const float* gb = glob + ((size_t)b*4096 + ch*256)*128;
  float4 a = {0.f, 0.f, 0.f, 0.f};
#pragma unroll
  for (int i = 0; i < 32; ++i){
    int r = rg + i*8;
    float4 v = *(const float4*)(gb + (size_t)r*128 + c4*4);
    a.x += v.x; a.y += v.y; a.z += v.z; a.w += v.w;
  }
  sh.part4[rg][c4] = a;
  __syncthreads();
  if (tid < 32){
    float4 s = sh.part4[0][tid];
#pragma unroll
    for (int g = 1; g < 8; ++g){
      float4 v = sh.part4[g][tid];
      s.x += v.x; s.y += v.y; s.z += v.z; s.w += v.w;
    }
    float* gm = gmean + b*128 + tid*4;
    atomicAdd(&gm[0], s.x); atomicAdd(&gm[1], s.y);
    atomicAdd(&gm[2], s.z); atomicAdd(&gm[3], s.w);
  }
}

// W [K][128] fp32 -> 16KB-window-ordered bf16 (frag = c*16 + nblk*2 + kk; 512 ushorts/frag)
__global__ __launch_bounds__(TPM) void k_prep(
    const float* __restrict__ Wp, const float* __restrict__ Wu,
    const float* __restrict__ Wg, const float* __restrict__ Wgl,
    unsigned short* __restrict__ WfP, unsigned short* __restrict__ WfU,
    unsigned short* __restrict__ WfG, unsigned short* __restrict__ WfGl){
  int e = blockIdx.x * TPM + threadIdx.x;      // 0..32767
  int j = e & 7, lane = (e >> 3) & 63, frag = e >> 9;
  int kk = frag & 1, nblk = (frag >> 1) & 7, c = frag >> 4;
  int il = lane & 15, lg = lane >> 4;
  int col = nblk*16 + il;
  int k = c*64 + kk*32 + lg*8 + j;
  if (e < 16384){
    WfP[e] = f2bf(Wp[k*128 + col]);
    WfU[e] = f2bf(Wu[k*128 + col]);
  }
  WfG[e]  = f2bf(Wg[k*128 + col]);
  WfGl[e] = f2bf(Wgl[k*128 + col]);
}

// ==========  mega body: R18's 10-phase, 4 waves / 64 rows (verified)  ==========
struct MegaSh {
  unsigned short wb[2][8192];      // 2 x 16 KB weight windows
  unsigned short ubuf[4][16*UPAD]; // per-wave u scratch (17.4 KB)
};                                 // 49.4 KB -> 3 blocks/CU
template<int PATH>   // 0 = fine path, 1 = coarse path
__device__ void mega_body(MegaSh& sh, int bid,
    const float* __restrict__ a_src,
    const float* __restrict__ gath_src,
    const unsigned short* __restrict__ x1b,
    const int* __restrict__ idx,
    const float* __restrict__ gsrc,
    float gscale,
    const unsigned short* __restrict__ Wf1, const float* __restrict__ b1,
    const float* __restrict__ g1, const float* __restrict__ be1,
    const unsigned short* __restrict__ WfG, const float* __restrict__ bG,
    const unsigned short* __restrict__ WfGl, const float* __restrict__ bGl,
    const float* __restrict__ gGl, const float* __restrict__ beGl,
    float* __restrict__ out)
{
  int tid = threadIdx.x;
  int wave = tid >> 6, lane = tid & 63;
  int il = lane & 15, lg = lane >> 4;
  int row0 = bid * 64 + wave * 16;
  int b = (PATH == 0) ? (row0 >> 12) : (row0 >> 9);
  unsigned short* u = sh.ubuf[wave];

  // ===== prologue: stage w0 (W1 lo) + A1 loads =====
  stage_win(Wf1, sh.wb[0], tid);
  bf16x8 a1[4];
  if (PATH == 0){
    int n0 = row0 & 4095;
    int ci = idx[b*4096 + n0 + il];
    bool valid = (unsigned)ci < 512u;
    const float* cr = gath_src + ((size_t)b*512 + (valid ? ci : 0))*128;
#pragma unroll
    for (int c = 0; c < 2; ++c)
#pragma unroll
      for (int kk = 0; kk < 2; ++kk){
        float4 f0 = {0.f,0.f,0.f,0.f}, f1 = {0.f,0.f,0.f,0.f};
        if (valid){
          f0 = *(const float4*)(cr + c*64 + kk*32 + lg*8);
          f1 = *(const float4*)(cr + c*64 + kk*32 + lg*8 + 4);
        }
        a1[c*2 + kk] = pack8(f0, f1);
      }
  } else {
    const unsigned short* pr = x1b + (size_t)(row0 + il)*128;
#pragma unroll
    for (int c = 0; c < 2; ++c)
#pragma unroll
      for (int kk = 0; kk < 2; ++kk)
        a1[c*2 + kk] = *(const bf16x8*)(pr + c*64 + kk*32 + lg*8);
  }
  __syncthreads();                              // w0 ready

  f32x4 acc[8] = {};
  bf16x8 af[2];
  float4 raw[8];
  const float* ar = a_src + (size_t)(row0 + il)*128;

  // ph0: stage w1 (W1 hi) | compute w0 (GEMM1 c0)
  stage_win(Wf1 + 8192, sh.wb[1], tid);
  af[0] = a1[0]; af[1] = a1[1];
  gemm_win(af, sh.wb[0], acc, lane);
  __syncthreads();

  // ph1: stage w2 (WG c0) | compute w1 (GEMM1 c1) + raw prefetch + LN1
  stage_win(WfG, sh.wb[0], tid);
  af[0] = a1[2]; af[1] = a1[3];
  gemm_win(af, sh.wb[1], acc, lane);
#pragma unroll
  for (int c = 0; c < 2; ++c)
#pragma unroll
    for (int kk = 0; kk < 2; ++kk){
      raw[(c*2+kk)*2+0] = *(const float4*)(ar + c*64 + kk*32 + lg*8);
      raw[(c*2+kk)*2+1] = *(const float4*)(ar + c*64 + kk*32 + lg*8 + 4);
    }
  {
    float bia[8], gmv[8], btv[8];
#pragma unroll
    for (int n = 0; n < 8; ++n){
      int col = n*16 + il;
      bia[n] = b1[col]; gmv[n] = g1[col]; btv[n] = be1[col];
    }
    float mean[4], rstd[4];
    rowstats(acc, bia, mean, rstd);
#pragma unroll
    for (int ri = 0; ri < 4; ++ri)
#pragma unroll
      for (int n = 0; n < 8; ++n){
        float z = acc[n][ri] + bia[n];
        float y = fmaxf((z - mean[ri])*rstd[ri]*gmv[n] + btv[n], 0.f);
        u[(lg*4 + ri)*UPAD + n*16 + il] = f2bf(y);
      }
  }
  __syncthreads();

  // ph2: stage w3 (WG c1) | compute w2 (GEMM2 c0 from a)
  stage_win(WfG + 8192, sh.wb[1], tid);
#pragma unroll
  for (int n = 0; n < 8; ++n) acc[n] = (f32x4){0.f,0.f,0.f,0.f};
  af[0] = pack8(raw[0], raw[1]); af[1] = pack8(raw[2], raw[3]);
  gemm_win(af, sh.wb[0], acc, lane);
  __syncthreads();

  // ph3: stage w4 (WG c2) | compute w3 (GEMM2 c1 from a)
  stage_win(WfG + 16384, sh.wb[0], tid);
  af[0] = pack8(raw[4], raw[5]); af[1] = pack8(raw[6], raw[7]);
  gemm_win(af, sh.wb[1], acc, lane);
  __syncthreads();

  // ph4: stage w5 (WG c3) | compute w4 (GEMM2 c2 from u1) + GEMM3-A prefetch
  stage_win(WfG + 24576, sh.wb[1], tid);
  if (PATH == 0){
    const float* gr = gsrc + (size_t)(row0 + il)*128;
#pragma unroll
    for (int c = 0; c < 2; ++c)
#pragma unroll
      for (int kk = 0; kk < 2; ++kk){
        raw[(c*2+kk)*2+0] = *(const float4*)(gr + c*64 + kk*32 + lg*8);
        raw[(c*2+kk)*2+1] = *(const float4*)(gr + c*64 + kk*32 + lg*8 + 4);
      }
  } else {
    const float* gm = gsrc + b*128;
#pragma unroll
    for (int c = 0; c < 2; ++c)
#pragma unroll
      for (int kk = 0; kk < 2; ++kk){
        float4 f0 = *(const float4*)(gm + c*64 + kk*32 + lg*8);
        float4 f1 = *(const float4*)(gm + c*64 + kk*32 + lg*8 + 4);
        raw[(c*2+kk)*2+0] = (float4){f0.x*gscale, f0.y*gscale, f0.z*gscale, f0.w*gscale};
        raw[(c*2+kk)*2+1] = (float4){f1.x*gscale, f1.y*gscale, f1.z*gscale, f1.w*gscale};
      }
  }
  af[0] = *(const bf16x8*)(u + il*UPAD + 0*64 + 0*32 + lg*8);
  af[1] = *(const bf16x8*)(u + il*UPAD + 0*64 + 1*32 + lg*8);
  gemm_win(af, sh.wb[0], acc, lane);
  __syncthreads();

  // ph5: stage w6 (WGl c0) | compute w5 (GEMM2 c3 from u1) + gate epilogue
  stage_win(WfGl, sh.wb[0], tid);
  af[0] = *(const bf16x8*)(u + il*UPAD + 1*64 + 0*32 + lg*8);
  af[1] = *(const bf16x8*)(u + il*UPAD + 1*64 + 1*32 + lg*8);
  gemm_win(af, sh.wb[1], acc, lane);
#pragma unroll
  for (int ri = 0; ri < 4; ++ri){
    int grow = (row0 + lg*4 + ri)*128;
#pragma unroll
    for (int n = 0; n < 8; ++n){
      int col = n*16 + il;
      float z = acc[n][ri] + bG[col];
      float gt = 1.f / (1.f + __expf(-z));
      float f  = a_src[(size_t)grow + col];
      int ua = (lg*4 + ri)*UPAD + col;
      float u1 = bf2f(u[ua]);
      u[ua] = f2bf(gt*f + (1.f - gt)*u1);       // own addr: per-lane RMW
    }
  }
  __syncthreads();

  // ph6: stage w7 (WGl c1) | compute w6 (GEMM3 c0 from u2)
  stage_win(WfGl + 8192, sh.wb[1], tid);
#pragma unroll
  for (int n = 0; n < 8; ++n) acc[n] = (f32x4){0.f,0.f,0.f,0.f};
  af[0] = *(const bf16x8*)(u + il*UPAD + 0*64 + 0*32 + lg*8);
  af[1] = *(const bf16x8*)(u + il*UPAD + 0*64 + 1*32 + lg*8);
  gemm_win(af, sh.wb[0], acc, lane);
  __syncthreads();

  // ph7: stage w8 (WGl c2) | compute w7 (GEMM3 c1 from u2)
  stage_win(WfGl + 16384, sh.wb[0], tid);
  af[0] = *(const bf16x8*)(u + il*UPAD + 1*64 + 0*32 + lg*8);
  af[1] = *(const bf16x8*)(u + il*UPAD + 1*64 + 1*32 + lg*8);
  gemm_win(af, sh.wb[1], acc, lane);
  __syncthreads();

  // ph8: stage w9 (WGl c3) | compute w8 (GEMM3 c2 from glob)
  stage_win(WfGl + 24576, sh.wb[1], tid);
  af[0] = pack8(raw[0], raw[1]); af[1] = pack8(raw[2], raw[3]);
  gemm_win(af, sh.wb[0], acc, lane);
  __syncthreads();

  // ph9: compute w9 (GEMM3 c3 from glob) + final epilogue
  af[0] = pack8(raw[4], raw[5]); af[1] = pack8(raw[6], raw[7]);
  gemm_win(af, sh.wb[1], acc, lane);
  {
    float bia[8], gmv[8], btv[8];
#pragma unroll
    for (int n = 0; n < 8; ++n){
      int col = n*16 + il;
      bia[n] = bGl[col]; gmv[n] = gGl[col]; btv[n] = beGl[col];
    }
    float mean[4], rstd[4];
    rowstats(acc, bia, mean, rstd);
#pragma unroll
    for (int ri = 0; ri < 4; ++ri){
      int grow = (row0 + lg*4 + ri)*128;
#pragma unroll
      for (int n = 0; n < 8; ++n){
        int col = n*16 + il;
        float z = acc[n][ri] + bia[n];
        float y = fmaxf((z - mean[ri])*rstd[ri]*gmv[n] + btv[n], 0.f);
        float u2 = bf2f(u[(lg*4 + ri)*UPAD + col]);
        out[(size_t)grow + col] = u2 + 0.1f*y;
      }
    }
  }
}

union MainSh { MegaSh m; PoolSh p; GmeanSh g; };

// Main dispatch, INTERLEAVED roles: each group of 7 consecutive blocks = 4 fine-mega + 3 aux.
// Aux blocks stay co-resident with mega throughout -> their HBM traffic fills mega's
// latency slack (R19 aux-last = tail; R20 aux-first = head; both serialized).
// pool/gmean outputs are consumed only by k_coarse (next dispatch) -> no ordering race.
__global__ __launch_bounds__(TPM, 3) void k_main(
    const float* __restrict__ fine,
    const float* __restrict__ coarse,
    const int* __restrict__ idx,
    const float* __restrict__ glob,
    const unsigned short* __restrict__ WfU, const float* __restrict__ bU,
    const float* __restrict__ gU, const float* __restrict__ beU,
    const unsigned short* __restrict__ WfG, const float* __restrict__ bG,
    const unsigned short* __restrict__ WfGl, const float* __restrict__ bGl,
    const float* __restrict__ gGl, const float* __restrict__ beGl,
    unsigned short* __restrict__ pooled,
    float* __restrict__ gmean,
    float* __restrict__ out_fine)
{
  __shared__ __align__(16) MainSh sh;
  int bid = blockIdx.x;
  int grp = bid / 7, rem = bid - grp*7;
  if (rem < 4){
    mega_body<0>(sh.m, grp*4 + rem, fine, coarse, nullptr, idx, glob, 1.0f,
                 WfU, bU, gU, beU, WfG, bG, WfGl, bGl, gGl, beGl, out_fine);
  } else {
    int aid = grp*3 + (rem - 4);
    if (aid < NPB) pool_body(sh.p, aid, fine, idx, pooled);
    else           gmean_body(sh.g, aid - NPB, glob, gmean);
  }
}

// coarse path dispatch (consumes pooled/gmean from k_main)
__global__ __launch_bounds__(TPM, 3) void k_coarse(
    const float* __restrict__ coarse,
    const unsigned short* __restrict__ pooled,
    const float* __restrict__ gmean,
    const unsigned short* __restrict__ WfP, const float* __restrict__ bP,
    const float* __restrict__ gP, const float* __restrict__ beP,
    const unsigned short* __restrict__ WfG, const float* __restrict__ bG,
    const unsigned short* __restrict__ WfGl, const float* __restrict__ bGl,
    const float* __restrict__ gGl, const float* __restrict__ beGl,
    float* __restrict__ out_coarse)
{
  __shared__ __align__(16) MegaSh sh;
  mega_body<1>(sh, blockIdx.x, coarse, nullptr, pooled, nullptr, gmean, 1.f/4096.f,
               WfP, bP, gP, beP, WfG, bG, WfGl, bGl, gGl, beGl, out_coarse);
}

extern "C" void kernel_launch(void* const* d_in, const int* in_sizes, int n_in,
                              void* d_out, int out_size, void* d_ws, size_t ws_size,
                              hipStream_t stream){
  const float* fine    = (const float*)d_in[0];
  const float* coarse  = (const float*)d_in[1];
  const float* glob    = (const float*)d_in[2];
  const int*   idx     = (const int*)  d_in[3];
  const float* W_pool  = (const float*)d_in[4];
  const float* b_pool  = (const float*)d_in[5];
  const float* g_pool  = (const float*)d_in[6];
  const float* be_pool = (const float*)d_in[7];
  const float* W_unpool  = (const float*)d_in[8];
  const float* b_unpool  = (const float*)d_in[9];
  const float* g_unpool  = (const float*)d_in[10];
  const float* be_unpool = (const float*)d_in[11];
  const float* W_gate = (const float*)d_in[12];
  const float* b_gate = (const float*)d_in[13];
  const float* W_glob = (const float*)d_in[14];
  const float* b_glob = (const float*)d_in[15];
  const float* g_glob = (const float*)d_in[16];
  const float* be_glob= (const float*)d_in[17];

  const int B = 32, N = 4096, C = 512;
  float* out_fine   = (float*)d_out;
  float* out_coarse = out_fine + (size_t)B*N*128;

  char* w = (char*)d_ws;
  unsigned short* WfP  = (unsigned short*)w; w += 16384*2;
  unsigned short* WfU  = (unsigned short*)w; w += 16384*2;
  unsigned short* WfG  = (unsigned short*)w; w += 32768*2;
  unsigned short* WfGl = (unsigned short*)w; w += 32768*2;
  float* gmean = (float*)w;                  w += B*128*4;
  unsigned short* pooled = (unsigned short*)w; w += (size_t)B*C*128*2;

  hipMemsetAsync(gmean, 0, B*128*4, stream);
  // 1) weight prep only (fine path's sole prologue dependency)
  k_prep<<<128, TPM, 0, stream>>>(W_pool, W_unpool, W_gate, W_glob, WfP, WfU, WfG, WfGl);

  // 2) main: fine-path mega interleaved 4:3 with pool+gmean aux blocks
  k_main<<<7*512, TPM, 0, stream>>>(
      fine, coarse, idx, glob,
      WfU, b_unpool, g_unpool, be_unpool,
      WfG, b_gate, WfGl, b_glob, g_glob, be_glob,
      pooled, gmean, out_fine);

  // 3) coarse path (needs pooled + gmean)
  k_coarse<<<NM1, TPM, 0, stream>>>(
      coarse, pooled, gmean,
      WfP, b_pool, g_pool, be_pool,
      WfG, b_gate, WfGl, b_glob, g_glob, be_glob,
      out_coarse);
}

// Round 22
// 98.492 us; speedup vs baseline: 1.0946x; 1.0821x over previous
//
#include <hip/hip_runtime.h>

typedef __bf16 bf16;
typedef bf16 bf16x8 __attribute__((ext_vector_type(8)));
typedef float f32x4 __attribute__((ext_vector_type(4)));

#define TPP 512    // k_pre block size
#define TPM 256    // mega block size (4 waves, 64 rows)
#define UPAD 136   // u-scratch row stride in ushorts

#define NPOOL 1024 // 32 batches x 32 groups of 16 clusters
#define NGM   512  // 32 batches x 16 chunks of 256 rows
#define NPREP 64   // 64 x 512 = 32768 weight elems
#define NM1   256  // coarse-path mega blocks: (32*512)/64
#define NM0   2048 // fine-path mega blocks: (32*4096)/64
// mega grid 2304 = 768 resident (3 blocks/CU x 256 CU) x 3.0 rounds exactly — no tail

__device__ inline unsigned short f2bf(float f){
  union{ bf16 h; unsigned short u; } v; v.h = (bf16)f; return v.u;
}
__device__ inline float bf2f(unsigned short u){
  union{ unsigned short u; bf16 h; } v; v.u = u; return (float)v.h;
}
__device__ inline unsigned int pk2(float a, float b){
  return (unsigned int)f2bf(a) | ((unsigned int)f2bf(b) << 16);
}
union BF8 { bf16x8 v; unsigned int u[4]; };
__device__ inline bf16x8 pack8(float4 a, float4 b){
  BF8 r; r.u[0] = pk2(a.x, a.y); r.u[1] = pk2(a.z, a.w);
  r.u[2] = pk2(b.x, b.y); r.u[3] = pk2(b.z, b.w); return r.v;
}

// ---- async global->LDS staging (no VGPR round-trip; drained by __syncthreads) ----
__device__ inline void gll16(const unsigned short* g, unsigned short* l){
  __builtin_amdgcn_global_load_lds(
      (const __attribute__((address_space(1))) unsigned int*)g,
      (__attribute__((address_space(3))) unsigned int*)l, 16, 0, 0);
}
// stage one 16KB half-window (16 frags of 512 ushorts): 4 gll16 per thread at 256 thr
__device__ inline void stage_win(const unsigned short* __restrict__ src,
                                 unsigned short* half, int tid){
#pragma unroll
  for (int i = 0; i < 4; ++i){
    int p = (tid + i*TPM)*8;
    gll16(src + p, half + p);
  }
}

// one 64-K chunk (16 MFMA) for a 16x128 wave tile; B from a 16KB half-window
__device__ inline void gemm_win(const bf16x8 a[2], const unsigned short* half,
                                f32x4 acc[8], int lane){
#pragma unroll
  for (int kk = 0; kk < 2; ++kk){
    bf16x8 av = a[kk];
#pragma unroll
    for (int n = 0; n < 8; ++n){
      bf16x8 bv = *(const bf16x8*)(half + (size_t)((n*2 + kk)*512) + lane*8);
      acc[n] = __builtin_amdgcn_mfma_f32_16x16x32_bf16(av, bv, acc[n], 0, 0, 0);
    }
  }
}

// per-row LN stats, in-wave (rows = lg*4+ri, cols = n*16+il)
__device__ inline void rowstats(const f32x4 acc[8], const float bia[8],
                                float mean[4], float rstd[4]){
#pragma unroll
  for (int ri = 0; ri < 4; ++ri){
    float s = 0.f, q = 0.f;
#pragma unroll
    for (int n = 0; n < 8; ++n){
      float z = acc[n][ri] + bia[n];
      s += z; q += z*z;
    }
#pragma unroll
    for (int m = 1; m < 16; m <<= 1){ s += __shfl_xor(s, m); q += __shfl_xor(q, m); }
    mean[ri] = s * (1.f/128.f);
    float var = q * (1.f/128.f) - mean[ri]*mean[ri];
    rstd[ri] = rsqrtf(var + 1e-5f);
  }
}

// =======================  prologue bodies (verified R14/R16/R18)  =======================
struct PoolSh {
  int sidx[4096];
  int rows[4096];
  int cnt[16], off[17], woff[16];
};
struct GmeanSh { float4 part4[16][32]; };
union PreSh { PoolSh p; GmeanSh g; };

__device__ void pool_body(PoolSh& sh, int pid,
                          const float* __restrict__ fine,
                          const int* __restrict__ idx,
                          unsigned short* __restrict__ pooled){
  int b = pid >> 5, g = pid & 31;
  int c0 = g * 16;
  int tid = threadIdx.x;
  const int* idx_b = idx + b*4096;
#pragma unroll
  for (int i = 0; i < 2; ++i)
    ((int4*)sh.sidx)[tid + i*TPP] = ((const int4*)idx_b)[tid + i*TPP];
  if (tid < 16) sh.cnt[tid] = 0;
  __syncthreads();
  for (int i = tid; i < 4096; i += TPP){
    unsigned d = (unsigned)(sh.sidx[i] - c0);
    if (d < 16u) atomicAdd(&sh.cnt[d], 1);
  }
  __syncthreads();
  if (tid == 0){
    int s = 0;
#pragma unroll
    for (int j = 0; j < 16; ++j){ sh.off[j] = s; s += sh.cnt[j]; }
    sh.off[16] = s;
  }
  __syncthreads();
  if (tid < 16) sh.woff[tid] = sh.off[tid];
  __syncthreads();
  for (int i = tid; i < 4096; i += TPP){
    unsigned d = (unsigned)(sh.sidx[i] - c0);
    if (d < 16u){ int p = atomicAdd(&sh.woff[d], 1); sh.rows[p] = i; }
  }
  __syncthreads();
  int hw = tid >> 5, l32 = tid & 31;
  const float* fb = fine + (size_t)b*4096*128;
  int o0 = sh.off[hw], o1 = sh.off[hw+1];
  float4 s = {0.f, 0.f, 0.f, 0.f};
  int m = o0;
  for (; m + 3 < o1; m += 4){
    float4 v0 = *((const float4*)(fb + (size_t)sh.rows[m+0]*128) + l32);
    float4 v1 = *((const float4*)(fb + (size_t)sh.rows[m+1]*128) + l32);
    float4 v2 = *((const float4*)(fb + (size_t)sh.rows[m+2]*128) + l32);
    float4 v3 = *((const float4*)(fb + (size_t)sh.rows[m+3]*128) + l32);
    s.x += (v0.x + v1.x) + (v2.x + v3.x);
    s.y += (v0.y + v1.y) + (v2.y + v3.y);
    s.z += (v0.z + v1.z) + (v2.z + v3.z);
    s.w += (v0.w + v1.w) + (v2.w + v3.w);
  }
  for (; m < o1; ++m){
    float4 v = *((const float4*)(fb + (size_t)sh.rows[m]*128) + l32);
    s.x += v.x; s.y += v.y; s.z += v.z; s.w += v.w;
  }
  float inv = 1.f / fmaxf((float)(o1 - o0), 1.f);
  unsigned short* po = pooled + ((size_t)(b*512 + c0 + hw))*128 + l32*4;
  uint2 w2; w2.x = pk2(s.x*inv, s.y*inv); w2.y = pk2(s.z*inv, s.w*inv);
  *(uint2*)po = w2;
}

__device__ void gmean_body(GmeanSh& sh, int gid,
                           const float* __restrict__ glob,
                           float* __restrict__ gmean){
  int b = gid >> 4, ch = gid & 15;
  int tid = threadIdx.x;
  int c4 = tid & 31, rg = tid >> 5;
  const float* gb = glob + ((size_t)b*4096 + ch*256)*128;
  float4 a = {0.f, 0.f, 0.f, 0.f};
#pragma unroll
  for (int i = 0; i < 16; ++i){
    int r = rg + i*16;
    float4 v = *(const float4*)(gb + (size_t)r*128 + c4*4);
    a.x += v.x; a.y += v.y; a.z += v.z; a.w += v.w;
  }
  sh.part4[rg][c4] = a;
  __syncthreads();
  if (tid < 32){
    float4 s = sh.part4[0][tid];
#pragma unroll
    for (int g = 1; g < 16; ++g){
      float4 v = sh.part4[g][tid];
      s.x += v.x; s.y += v.y; s.z += v.z; s.w += v.w;
    }
    float* gm = gmean + b*128 + tid*4;
    atomicAdd(&gm[0], s.x); atomicAdd(&gm[1], s.y);
    atomicAdd(&gm[2], s.z); atomicAdd(&gm[3], s.w);
  }
}

// W [K][128] fp32 -> 16KB-window-ordered bf16 (frag = c*16 + nblk*2 + kk; 512 ushorts/frag)
__device__ void prep_body(int e,
                          const float* __restrict__ Wp, const float* __restrict__ Wu,
                          const float* __restrict__ Wg, const float* __restrict__ Wgl,
                          unsigned short* __restrict__ WfP, unsigned short* __restrict__ WfU,
                          unsigned short* __restrict__ WfG, unsigned short* __restrict__ WfGl){
  int j = e & 7, lane = (e >> 3) & 63, frag = e >> 9;
  int kk = frag & 1, nblk = (frag >> 1) & 7, c = frag >> 4;
  int il = lane & 15, lg = lane >> 4;
  int col = nblk*16 + il;
  int k = c*64 + kk*32 + lg*8 + j;
  if (e < 16384){
    WfP[e] = f2bf(Wp[k*128 + col]);
    WfU[e] = f2bf(Wu[k*128 + col]);
  }
  WfG[e]  = f2bf(Wg[k*128 + col]);
  WfGl[e] = f2bf(Wgl[k*128 + col]);
}

// fused prologue dispatch: pool + gmean + prep, role by blockIdx (all small-LDS)
__global__ __launch_bounds__(TPP) void k_pre(
    const float* __restrict__ fine, const int* __restrict__ idx,
    const float* __restrict__ glob,
    const float* __restrict__ Wp, const float* __restrict__ Wu,
    const float* __restrict__ Wg, const float* __restrict__ Wgl,
    unsigned short* __restrict__ pooled, float* __restrict__ gmean,
    unsigned short* __restrict__ WfP, unsigned short* __restrict__ WfU,
    unsigned short* __restrict__ WfG, unsigned short* __restrict__ WfGl){
  __shared__ __align__(16) PreSh sh;
  int bid = blockIdx.x;
  if (bid < NPOOL)             pool_body(sh.p, bid, fine, idx, pooled);
  else if (bid < NPOOL + NGM)  gmean_body(sh.g, bid - NPOOL, glob, gmean);
  else                         prep_body((bid - NPOOL - NGM)*TPP + threadIdx.x,
                                         Wp, Wu, Wg, Wgl, WfP, WfU, WfG, WfGl);
}

// ==========  mega: 10-phase body at 4 waves / 64 rows, 3 blocks/CU (verified R18)  ==========
struct MegaSh {
  unsigned short wb[2][8192];      // 2 x 16 KB weight windows
  unsigned short ubuf[4][16*UPAD]; // per-wave u scratch (17.4 KB)
};                                 // 49.4 KB -> 3 blocks/CU
template<int PATH>   // 0 = fine path, 1 = coarse path
__device__ void mega_body(MegaSh& sh, int bid,
    const float* __restrict__ a_src,
    const float* __restrict__ gath_src,
    const unsigned short* __restrict__ x1b,
    const int* __restrict__ idx,
    const float* __restrict__ gsrc,
    float gscale,
    const unsigned short* __restrict__ Wf1, const float* __restrict__ b1,
    const float* __restrict__ g1, const float* __restrict__ be1,
    const unsigned short* __restrict__ WfG, const float* __restrict__ bG,
    const unsigned short* __restrict__ WfGl, const float* __restrict__ bGl,
    const float* __restrict__ gGl, const float* __restrict__ beGl,
    float* __restrict__ out)
{
  int tid = threadIdx.x;
  int wave = tid >> 6, lane = tid & 63;
  int il = lane & 15, lg = lane >> 4;
  int row0 = bid * 64 + wave * 16;
  int b = (PATH == 0) ? (row0 >> 12) : (row0 >> 9);
  unsigned short* u = sh.ubuf[wave];

  // ===== prologue: stage w0 (W1 lo) + A1 loads =====
  stage_win(Wf1, sh.wb[0], tid);
  bf16x8 a1[4];
  if (PATH == 0){
    int n0 = row0 & 4095;
    int ci = idx[b*4096 + n0 + il];
    bool valid = (unsigned)ci < 512u;
    const float* cr = gath_src + ((size_t)b*512 + (valid ? ci : 0))*128;
#pragma unroll
    for (int c = 0; c < 2; ++c)
#pragma unroll
      for (int kk = 0; kk < 2; ++kk){
        float4 f0 = {0.f,0.f,0.f,0.f}, f1 = {0.f,0.f,0.f,0.f};
        if (valid){
          f0 = *(const float4*)(cr + c*64 + kk*32 + lg*8);
          f1 = *(const float4*)(cr + c*64 + kk*32 + lg*8 + 4);
        }
        a1[c*2 + kk] = pack8(f0, f1);
      }
  } else {
    const unsigned short* pr = x1b + (size_t)(row0 + il)*128;
#pragma unroll
    for (int c = 0; c < 2; ++c)
#pragma unroll
      for (int kk = 0; kk < 2; ++kk)
        a1[c*2 + kk] = *(const bf16x8*)(pr + c*64 + kk*32 + lg*8);
  }
  __syncthreads();                              // w0 ready

  f32x4 acc[8] = {};
  bf16x8 af[2];
  float4 raw[8];
  const float* ar = a_src + (size_t)(row0 + il)*128;

  // ph0: stage w1 (W1 hi) | compute w0 (GEMM1 c0)
  stage_win(Wf1 + 8192, sh.wb[1], tid);
  af[0] = a1[0]; af[1] = a1[1];
  gemm_win(af, sh.wb[0], acc, lane);
  __syncthreads();

  // ph1: stage w2 (WG c0) | compute w1 (GEMM1 c1) + raw prefetch + LN1
  stage_win(WfG, sh.wb[0], tid);
  af[0] = a1[2]; af[1] = a1[3];
  gemm_win(af, sh.wb[1], acc, lane);
#pragma unroll
  for (int c = 0; c < 2; ++c)
#pragma unroll
    for (int kk = 0; kk < 2; ++kk){
      raw[(c*2+kk)*2+0] = *(const float4*)(ar + c*64 + kk*32 + lg*8);
      raw[(c*2+kk)*2+1] = *(const float4*)(ar + c*64 + kk*32 + lg*8 + 4);
    }
  {
    float bia[8], gmv[8], btv[8];
#pragma unroll
    for (int n = 0; n < 8; ++n){
      int col = n*16 + il;
      bia[n] = b1[col]; gmv[n] = g1[col]; btv[n] = be1[col];
    }
    float mean[4], rstd[4];
    rowstats(acc, bia, mean, rstd);
#pragma unroll
    for (int ri = 0; ri < 4; ++ri)
#pragma unroll
      for (int n = 0; n < 8; ++n){
        float z = acc[n][ri] + bia[n];
        float y = fmaxf((z - mean[ri])*rstd[ri]*gmv[n] + btv[n], 0.f);
        u[(lg*4 + ri)*UPAD + n*16 + il] = f2bf(y);
      }
  }
  __syncthreads();

  // ph2: stage w3 (WG c1) | compute w2 (GEMM2 c0 from a)
  stage_win(WfG + 8192, sh.wb[1], tid);
#pragma unroll
  for (int n = 0; n < 8; ++n) acc[n] = (f32x4){0.f,0.f,0.f,0.f};
  af[0] = pack8(raw[0], raw[1]); af[1] = pack8(raw[2], raw[3]);
  gemm_win(af, sh.wb[0], acc, lane);
  __syncthreads();

  // ph3: stage w4 (WG c2) | compute w3 (GEMM2 c1 from a)
  stage_win(WfG + 16384, sh.wb[0], tid);
  af[0] = pack8(raw[4], raw[5]); af[1] = pack8(raw[6], raw[7]);
  gemm_win(af, sh.wb[1], acc, lane);
  __syncthreads();

  // ph4: stage w5 (WG c3) | compute w4 (GEMM2 c2 from u1) + GEMM3-A prefetch
  stage_win(WfG + 24576, sh.wb[1], tid);
  if (PATH == 0){
    const float* gr = gsrc + (size_t)(row0 + il)*128;
#pragma unroll
    for (int c = 0; c < 2; ++c)
#pragma unroll
      for (int kk = 0; kk < 2; ++kk){
        raw[(c*2+kk)*2+0] = *(const float4*)(gr + c*64 + kk*32 + lg*8);
        raw[(c*2+kk)*2+1] = *(const float4*)(gr + c*64 + kk*32 + lg*8 + 4);
      }
  } else {
    const float* gm = gsrc + b*128;
#pragma unroll
    for (int c = 0; c < 2; ++c)
#pragma unroll
      for (int kk = 0; kk < 2; ++kk){
        float4 f0 = *(const float4*)(gm + c*64 + kk*32 + lg*8);
        float4 f1 = *(const float4*)(gm + c*64 + kk*32 + lg*8 + 4);
        raw[(c*2+kk)*2+0] = (float4){f0.x*gscale, f0.y*gscale, f0.z*gscale, f0.w*gscale};
        raw[(c*2+kk)*2+1] = (float4){f1.x*gscale, f1.y*gscale, f1.z*gscale, f1.w*gscale};
      }
  }
  af[0] = *(const bf16x8*)(u + il*UPAD + 0*64 + 0*32 + lg*8);
  af[1] = *(const bf16x8*)(u + il*UPAD + 0*64 + 1*32 + lg*8);
  gemm_win(af, sh.wb[0], acc, lane);
  __syncthreads();

  // ph5: stage w6 (WGl c0) | compute w5 (GEMM2 c3 from u1) + gate epilogue
  stage_win(WfGl, sh.wb[0], tid);
  af[0] = *(const bf16x8*)(u + il*UPAD + 1*64 + 0*32 + lg*8);
  af[1] = *(const bf16x8*)(u + il*UPAD + 1*64 + 1*32 + lg*8);
  gemm_win(af, sh.wb[1], acc, lane);
#pragma unroll
  for (int ri = 0; ri < 4; ++ri){
    int grow = (row0 + lg*4 + ri)*128;
#pragma unroll
    for (int n = 0; n < 8; ++n){
      int col = n*16 + il;
      float z = acc[n][ri] + bG[col];
      float gt = 1.f / (1.f + __expf(-z));
      float f  = a_src[(size_t)grow + col];
      int ua = (lg*4 + ri)*UPAD + col;
      float u1 = bf2f(u[ua]);
      u[ua] = f2bf(gt*f + (1.f - gt)*u1);       // own addr: per-lane RMW
    }
  }
  __syncthreads();

  // ph6: stage w7 (WGl c1) | compute w6 (GEMM3 c0 from u2)
  stage_win(WfGl + 8192, sh.wb[1], tid);
#pragma unroll
  for (int n = 0; n < 8; ++n) acc[n] = (f32x4){0.f,0.f,0.f,0.f};
  af[0] = *(const bf16x8*)(u + il*UPAD + 0*64 + 0*32 + lg*8);
  af[1] = *(const bf16x8*)(u + il*UPAD + 0*64 + 1*32 + lg*8);
  gemm_win(af, sh.wb[0], acc, lane);
  __syncthreads();

  // ph7: stage w8 (WGl c2) | compute w7 (GEMM3 c1 from u2)
  stage_win(WfGl + 16384, sh.wb[0], tid);
  af[0] = *(const bf16x8*)(u + il*UPAD + 1*64 + 0*32 + lg*8);
  af[1] = *(const bf16x8*)(u + il*UPAD + 1*64 + 1*32 + lg*8);
  gemm_win(af, sh.wb[1], acc, lane);
  __syncthreads();

  // ph8: stage w9 (WGl c3) | compute w8 (GEMM3 c2 from glob)
  stage_win(WfGl + 24576, sh.wb[1], tid);
  af[0] = pack8(raw[0], raw[1]); af[1] = pack8(raw[2], raw[3]);
  gemm_win(af, sh.wb[0], acc, lane);
  __syncthreads();

  // ph9: compute w9 (GEMM3 c3 from glob) + final epilogue
  af[0] = pack8(raw[4], raw[5]); af[1] = pack8(raw[6], raw[7]);
  gemm_win(af, sh.wb[1], acc, lane);
  {
    float bia[8], gmv[8], btv[8];
#pragma unroll
    for (int n = 0; n < 8; ++n){
      int col = n*16 + il;
      bia[n] = bGl[col]; gmv[n] = gGl[col]; btv[n] = beGl[col];
    }
    float mean[4], rstd[4];
    rowstats(acc, bia, mean, rstd);
#pragma unroll
    for (int ri = 0; ri < 4; ++ri){
      int grow = (row0 + lg*4 + ri)*128;
#pragma unroll
      for (int n = 0; n < 8; ++n){
        int col = n*16 + il;
        float z = acc[n][ri] + bia[n];
        float y = fmaxf((z - mean[ri])*rstd[ri]*gmv[n] + btv[n], 0.f);
        float u2 = bf2f(u[(lg*4 + ri)*UPAD + col]);
        out[(size_t)grow + col] = u2 + 0.1f*y;
      }
    }
  }
}

// Merged mega dispatch: [0,NM1) coarse path, [NM1, NM1+NM0) fine path.
__global__ __launch_bounds__(TPM, 3) void k_mega(
    const float* __restrict__ fine,
    const float* __restrict__ coarse,
    const int* __restrict__ idx,
    const float* __restrict__ glob,
    const unsigned short* __restrict__ pooled,
    const float* __restrict__ gmean,
    const unsigned short* __restrict__ WfP, const float* __restrict__ bP,
    const float* __restrict__ gP, const float* __restrict__ beP,
    const unsigned short* __restrict__ WfU, const float* __restrict__ bU,
    const float* __restrict__ gU, const float* __restrict__ beU,
    const unsigned short* __restrict__ WfG, const float* __restrict__ bG,
    const unsigned short* __restrict__ WfGl, const float* __restrict__ bGl,
    const float* __restrict__ gGl, const float* __restrict__ beGl,
    float* __restrict__ out_fine,
    float* __restrict__ out_coarse)
{
  __shared__ __align__(16) MegaSh sh;
  int bid = blockIdx.x;
  if (bid < NM1){
    mega_body<1>(sh, bid, coarse, nullptr, pooled, nullptr, gmean, 1.f/4096.f,
                 WfP, bP, gP, beP, WfG, bG, WfGl, bGl, gGl, beGl, out_coarse);
  } else {
    mega_body<0>(sh, bid - NM1, fine, coarse, nullptr, idx, glob, 1.0f,
                 WfU, bU, gU, beU, WfG, bG, WfGl, bGl, gGl, beGl, out_fine);
  }
}

extern "C" void kernel_launch(void* const* d_in, const int* in_sizes, int n_in,
                              void* d_out, int out_size, void* d_ws, size_t ws_size,
                              hipStream_t stream){
  const float* fine    = (const float*)d_in[0];
  const float* coarse  = (const float*)d_in[1];
  const float* glob    = (const float*)d_in[2];
  const int*   idx     = (const int*)  d_in[3];
  const float* W_pool  = (const float*)d_in[4];
  const float* b_pool  = (const float*)d_in[5];
  const float* g_pool  = (const float*)d_in[6];
  const float* be_pool = (const float*)d_in[7];
  const float* W_unpool  = (const float*)d_in[8];
  const float* b_unpool  = (const float*)d_in[9];
  const float* g_unpool  = (const float*)d_in[10];
  const float* be_unpool = (const float*)d_in[11];
  const float* W_gate = (const float*)d_in[12];
  const float* b_gate = (const float*)d_in[13];
  const float* W_glob = (const float*)d_in[14];
  const float* b_glob = (const float*)d_in[15];
  const float* g_glob = (const float*)d_in[16];
  const float* be_glob= (const float*)d_in[17];

  const int B = 32, N = 4096, C = 512;
  float* out_fine   = (float*)d_out;
  float* out_coarse = out_fine + (size_t)B*N*128;

  char* w = (char*)d_ws;
  unsigned short* WfP  = (unsigned short*)w; w += 16384*2;
  unsigned short* WfU  = (unsigned short*)w; w += 16384*2;
  unsigned short* WfG  = (unsigned short*)w; w += 32768*2;
  unsigned short* WfGl = (unsigned short*)w; w += 32768*2;
  float* gmean = (float*)w;                  w += B*128*4;
  unsigned short* pooled = (unsigned short*)w; w += (size_t)B*C*128*2;

  hipMemsetAsync(gmean, 0, B*128*4, stream);
  // fused prologue: pool + gmean + prep (small-LDS blocks keep natural occupancy)
  k_pre<<<NPOOL + NGM + NPREP, TPP, 0, stream>>>(
      fine, idx, glob, W_pool, W_unpool, W_gate, W_glob,
      pooled, gmean, WfP, WfU, WfG, WfGl);

  // merged mega: coarse-path blocks first, then fine-path blocks
  k_mega<<<NM1 + NM0, TPM, 0, stream>>>(
      fine, coarse, idx, glob, pooled, gmean,
      WfP, b_pool, g_pool, be_pool,
      WfU, b_unpool, g_unpool, be_unpool,
      WfG, b_gate, WfGl, b_glob, g_glob, be_glob,
      out_fine, out_coarse);
}